// Round 6
// baseline (295.079 us; speedup 1.0000x reference)
//
#include <hip/hip_runtime.h>
#include <math.h>

#define NB    32768
#define DDIM  64
#define HDIM  512
#define PDIM  23        // 3*K - 1
#define KBINS 8
#define BM    32
#define NCOLS (DDIM * PDIM)   // 1472
#define CHUNK 368             // 16 d's worth of params = 8 waves x 46 cols
#define STRIPW 46             // cols per wave strip (2 d's)
#define PSTRIDE 47            // f32 stride per staged row (47%32=15, gcd 32 = 1)

#define RQ_BOUND  4.0f
#define RQ_MINBIN 0.001f
#define RQ_MINDER 0.001f

typedef __attribute__((ext_vector_type(8))) _Float16 half8;
typedef __attribute__((ext_vector_type(4))) float f32x4;
typedef unsigned short ushort_t;

// ---------------------------------------------------------------------------
// prep: bake masks, convert to fp16.  M1[h,i] = i <= h%63 ; M2[o,h] = o/23 > h%63
// ---------------------------------------------------------------------------
__global__ __launch_bounds__(256) void prep_f16(const float* __restrict__ W1,
                                                const float* __restrict__ W2,
                                                _Float16* __restrict__ W1f,
                                                _Float16* __restrict__ W2f) {
    int idx = blockIdx.x * 256 + threadIdx.x;
    const int n1 = HDIM * DDIM;          // 32768
    if (idx < n1) {
        int h = idx >> 6, i = idx & 63;
        W1f[idx] = (_Float16)((i <= (h % 63)) ? W1[idx] : 0.0f);
    } else {
        int j = idx - n1;
        if (j < NCOLS * HDIM) {
            int o = j >> 9, hh = j & 511;
            W2f[j] = (_Float16)(((o / PDIM) > (hh % 63)) ? W2[j] : 0.0f);
        }
    }
}

// ---------------------------------------------------------------------------
// fast transcendentals (validated round 5)
// ---------------------------------------------------------------------------
__device__ __forceinline__ float fexp(float v)  { return __expf(v); }
__device__ __forceinline__ float flog(float v)  { return __logf(v); }
__device__ __forceinline__ float fdiv(float a, float b) { return __fdividef(a, b); }

// ---------------------------------------------------------------------------
// rational-quadratic spline (validated rounds 1-5)
// ---------------------------------------------------------------------------
__device__ __forceinline__ void rqs_eval(const float* prm, float xorig,
                                         float& yo, float& ldo) {
    const float xc = fminf(fmaxf(xorig, -RQ_BOUND), RQ_BOUND);
    const bool inside = (xorig >= -RQ_BOUND) && (xorig <= RQ_BOUND);

    float xk[KBINS + 1], yk[KBINS + 1], dd[KBINS + 1];
    {
        float m = prm[0];
        #pragma unroll
        for (int i = 1; i < KBINS; ++i) m = fmaxf(m, prm[i]);
        float e[KBINS]; float s = 0.0f;
        #pragma unroll
        for (int i = 0; i < KBINS; ++i) { e[i] = fexp(prm[i] - m); s += e[i]; }
        const float inv = fdiv(1.0f, s);
        float c = 0.0f;
        xk[0] = -RQ_BOUND;
        #pragma unroll
        for (int i = 0; i < KBINS; ++i) {
            float w = RQ_MINBIN + (1.0f - RQ_MINBIN * KBINS) * (e[i] * inv);
            c += w;
            xk[i + 1] = -RQ_BOUND + 2.0f * RQ_BOUND * c;
        }
        xk[KBINS] = RQ_BOUND;
    }
    {
        float m = prm[8];
        #pragma unroll
        for (int i = 1; i < KBINS; ++i) m = fmaxf(m, prm[8 + i]);
        float e[KBINS]; float s = 0.0f;
        #pragma unroll
        for (int i = 0; i < KBINS; ++i) { e[i] = fexp(prm[8 + i] - m); s += e[i]; }
        const float inv = fdiv(1.0f, s);
        float c = 0.0f;
        yk[0] = -RQ_BOUND;
        #pragma unroll
        for (int i = 0; i < KBINS; ++i) {
            float h = RQ_MINBIN + (1.0f - RQ_MINBIN * KBINS) * (e[i] * inv);
            c += h;
            yk[i + 1] = -RQ_BOUND + 2.0f * RQ_BOUND * c;
        }
        yk[KBINS] = RQ_BOUND;
    }
    dd[0] = 1.0f;
    #pragma unroll
    for (int i = 0; i < KBINS - 1; ++i) {
        const float v = prm[16 + i];
        const float e = fexp(-fabsf(v));
        dd[i + 1] = RQ_MINDER + flog(1.0f + e) + fmaxf(v, 0.0f);
    }
    dd[KBINS] = 1.0f;

    int idx = 0;
    #pragma unroll
    for (int i = 1; i < KBINS; ++i) idx += (xc >= xk[i]) ? 1 : 0;

    float x_k = xk[0], x_k1 = xk[1];
    float y_k = yk[0], y_k1 = yk[1];
    float d_k = dd[0], d_k1 = dd[1];
    #pragma unroll
    for (int i = 1; i < KBINS; ++i) {
        const bool mm = (idx == i);
        x_k  = mm ? xk[i]     : x_k;
        x_k1 = mm ? xk[i + 1] : x_k1;
        y_k  = mm ? yk[i]     : y_k;
        y_k1 = mm ? yk[i + 1] : y_k1;
        d_k  = mm ? dd[i]     : d_k;
        d_k1 = mm ? dd[i + 1] : d_k1;
    }

    const float w_k = x_k1 - x_k;
    const float h_k = y_k1 - y_k;
    const float rw  = fdiv(1.0f, w_k);
    const float s   = h_k * rw;
    const float th  = (xc - x_k) * rw;
    const float omt = 1.0f - th;
    const float t1m = th * omt;
    const float num = h_k * (s * th * th + d_k * t1m);
    const float den = s + (d_k1 + d_k - 2.0f * s) * t1m;
    const float yin = y_k + fdiv(num, den);
    const float dnum = s * s * (d_k1 * th * th + 2.0f * s * t1m + d_k * omt * omt);
    const float ldin = flog(dnum) - 2.0f * flog(den);

    yo  = inside ? yin : xorig;
    ldo = inside ? ldin : 0.0f;
}

// ---------------------------------------------------------------------------
// fused fp16 MFMA kernel: 32 rows/block, 512 threads (8 waves), 2 blocks/CU.
// Phase 2 is BARRIER-FREE: wave wv owns the 46-col strip [46wv,46wv+46) of
// each 368-col chunk (3 MFMA tiles, last wave's 3rd tile clamped), stages it
// into a wave-PRIVATE pstage slice, and runs 64 spline evals (one per lane:
// row=lane&31, d = c*16 + 2wv + (lane>>5)). Same-wave LDS write->read needs
// no __syncthreads; waves drift freely so MFMA / L2-stream / spline-VALU of
// different waves overlap. Only 3 barriers total (post-GEMM1 + logdet reduce).
// ---------------------------------------------------------------------------
__global__ __launch_bounds__(512, 4) void fused_flow(
    const float* __restrict__ x,  const float* __restrict__ b1,
    const float* __restrict__ b2, const _Float16* __restrict__ W1f,
    const _Float16* __restrict__ W2f,
    float* __restrict__ z_out, float* __restrict__ ld_out)
{
    __shared__ __align__(16) ushort_t hm[BM * 512];            // 32 KB, swizzled
    __shared__ __align__(16) float pstage[8 * BM * PSTRIDE];   // 47 KB (8 strips)
    // total 79.0 KB -> 2 blocks/CU; pstage reused as ldbuf[32][8] at the end

    const int t    = threadIdx.x;
    const int row0 = blockIdx.x * BM;
    const int wv   = t >> 6;
    const int lane = t & 63;
    const int l15  = lane & 15;
    const int lg   = lane >> 4;

    char*  hmB = (char*)hm;
    float* pw  = pstage + wv * (BM * PSTRIDE);   // this wave's private strip

    // ---- phase 1: GEMM1 (x from global, W1f from global) -> hm fp16 ----
    {
        f32x4 acc1[4][2];
        #pragma unroll
        for (int j = 0; j < 4; ++j)
            #pragma unroll
            for (int m = 0; m < 2; ++m) acc1[j][m] = (f32x4){0.f, 0.f, 0.f, 0.f};

        #pragma unroll
        for (int kt = 0; kt < 2; ++kt) {
            half8 a[2];
            #pragma unroll
            for (int m = 0; m < 2; ++m) {
                const float* xr = x + (size_t)(row0 + m * 16 + l15) * DDIM + kt * 32 + lg * 8;
                const float4 xa = *(const float4*)(xr);
                const float4 xb = *(const float4*)(xr + 4);
                a[m][0] = (_Float16)xa.x; a[m][1] = (_Float16)xa.y;
                a[m][2] = (_Float16)xa.z; a[m][3] = (_Float16)xa.w;
                a[m][4] = (_Float16)xb.x; a[m][5] = (_Float16)xb.y;
                a[m][6] = (_Float16)xb.z; a[m][7] = (_Float16)xb.w;
            }
            #pragma unroll
            for (int j = 0; j < 4; ++j) {
                const int h = (wv * 4 + j) * 16 + l15;
                const half8 b = *(const half8*)(W1f + h * 64 + kt * 32 + lg * 8);
                #pragma unroll
                for (int m = 0; m < 2; ++m)
                    acc1[j][m] = __builtin_amdgcn_mfma_f32_16x16x32_f16(a[m], b, acc1[j][m], 0, 0, 0);
            }
        }
        #pragma unroll
        for (int j = 0; j < 4; ++j) {
            const int h = (wv * 4 + j) * 16 + l15;
            const float bias = b1[h];
            #pragma unroll
            for (int m = 0; m < 2; ++m) {
                #pragma unroll
                for (int q = 0; q < 4; ++q) {
                    const int r = m * 16 + lg * 4 + q;
                    const _Float16 hv = (_Float16)fmaxf(acc1[j][m][q] + bias, 0.0f);
                    *(ushort_t*)(hmB + r * 1024 + ((h * 2) ^ ((r & 7) << 4))) =
                        __builtin_bit_cast(ushort_t, hv);
                }
            }
        }
    }
    __syncthreads();   // hm is read-only from here on

    // ---- phase 2: per-wave GEMM2 strip + spline, 4 chunks, no barriers ----
    float ldacc = 0.0f;
    const int srow = lane & 31;   // spline row
    const int hi   = lane >> 5;   // spline d-within-strip (0/1)

    // tile bases within chunk (clamped so wave 7's 3rd tile stays in-chunk;
    // duplicated cols rewrite identical values)
    int tb[3];
    #pragma unroll
    for (int i = 0; i < 3; ++i) {
        const int b = STRIPW * wv + 16 * i;
        tb[i] = (b > CHUNK - 16) ? (CHUNK - 16) : b;
    }

    for (int c = 0; c < 4; ++c) {
        f32x4 acc[3][2];
        #pragma unroll
        for (int i = 0; i < 3; ++i)
            #pragma unroll
            for (int m = 0; m < 2; ++m) acc[i][m] = (f32x4){0.f, 0.f, 0.f, 0.f};

        const _Float16* w2p[3];
        #pragma unroll
        for (int i = 0; i < 3; ++i)
            w2p[i] = W2f + (size_t)(c * CHUNK + tb[i] + l15) * HDIM;

        #pragma unroll
        for (int kt = 0; kt < 16; ++kt) {
            half8 ah[2];
            #pragma unroll
            for (int m = 0; m < 2; ++m) {
                const int r  = m * 16 + l15;
                const int kb = (kt * 32 + lg * 8) * 2;
                ah[m] = *(const half8*)(hmB + r * 1024 + (kb ^ ((r & 7) << 4)));
            }
            half8 bfr[3];
            #pragma unroll
            for (int i = 0; i < 3; ++i)
                bfr[i] = *(const half8*)(w2p[i] + kt * 32 + lg * 8);
            #pragma unroll
            for (int i = 0; i < 3; ++i)
                #pragma unroll
                for (int m = 0; m < 2; ++m)
                    acc[i][m] = __builtin_amdgcn_mfma_f32_16x16x32_f16(ah[m], bfr[i], acc[i][m], 0, 0, 0);
        }

        // stage strip (wave-private; no barrier needed)
        #pragma unroll
        for (int i = 0; i < 3; ++i) {
            const int lcol = tb[i] + l15 - STRIPW * wv;   // 0..47 (dups identical)
            if (lcol < STRIPW) {
                #pragma unroll
                for (int m = 0; m < 2; ++m)
                    #pragma unroll
                    for (int q = 0; q < 4; ++q)
                        pw[(m * 16 + lg * 4 + q) * PSTRIDE + lcol] = acc[i][m][q];
            }
        }

        // spline: one (row, d) per lane (compiler orders LDS write->read)
        {
            const int d = c * 16 + 2 * wv + hi;
            float prm[PDIM];
            #pragma unroll
            for (int p = 0; p < PDIM; ++p)
                prm[p] = pw[srow * PSTRIDE + hi * PDIM + p] + b2[d * PDIM + p];
            const float xv = x[(size_t)(row0 + srow) * DDIM + d];
            float yv, lv;
            rqs_eval(prm, xv, yv, lv);
            z_out[(size_t)(row0 + srow) * DDIM + d] = yv;
            ldacc += lv;
        }
    }

    // ---- logdet: lane&31 pairs share a row; then cross-wave via reused pstage
    ldacc += __shfl_xor(ldacc, 32, 64);
    __syncthreads();                          // all waves done with pstage
    if (lane < 32) pstage[srow * 8 + wv] = ldacc;
    __syncthreads();
    if (t < BM) {
        float s = 0.0f;
        #pragma unroll
        for (int w = 0; w < 8; ++w) s += pstage[t * 8 + w];
        ld_out[row0 + t] = s;
    }
}

// ---------------------------------------------------------------------------
extern "C" void kernel_launch(void* const* d_in, const int* in_sizes, int n_in,
                              void* d_out, int out_size, void* d_ws, size_t ws_size,
                              hipStream_t stream) {
    (void)in_sizes; (void)n_in; (void)out_size; (void)ws_size;
    const float* x  = (const float*)d_in[0];
    const float* W1 = (const float*)d_in[1];
    const float* b1 = (const float*)d_in[2];
    const float* W2 = (const float*)d_in[3];
    const float* b2 = (const float*)d_in[4];

    _Float16* W1f = (_Float16*)d_ws;                 // 32768 fp16
    _Float16* W2f = W1f + HDIM * DDIM;               // 753664 fp16 (total ~1.57 MB)
    float* z  = (float*)d_out;
    float* ld = z + (size_t)NB * DDIM;

    const int n_prep = HDIM * DDIM + NCOLS * HDIM;   // 786432
    prep_f16<<<(n_prep + 255) / 256, 256, 0, stream>>>(W1, W2, W1f, W2f);
    fused_flow<<<NB / BM, 512, 0, stream>>>(x, b1, b2, W1f, W2f, z, ld);
}

// Round 7
// 239.004 us; speedup vs baseline: 1.2346x; 1.2346x over previous
//
#include <hip/hip_runtime.h>
#include <math.h>

#define NB    32768
#define DDIM  64
#define HDIM  512
#define PDIM  23        // 3*K - 1
#define KBINS 8
#define BM    32
#define NCOLS (DDIM * PDIM)   // 1472
#define CHUNK 368             // 16 d's worth of params = 8 waves x 46 cols
#define STRIPW 46             // cols per wave strip (2 d's)
#define PSTRIDE 47            // f32 stride per staged row

#define RQ_BOUND  4.0f
#define RQ_MINBIN 0.001f
#define RQ_MINDER 0.001f

typedef __attribute__((ext_vector_type(8))) _Float16 half8;
typedef __attribute__((ext_vector_type(4))) float f32x4;
typedef unsigned short ushort_t;

// ---------------------------------------------------------------------------
// prep: bake masks, convert to fp16.  M1[h,i] = i <= h%63 ; M2[o,h] = o/23 > h%63
// ---------------------------------------------------------------------------
__global__ __launch_bounds__(256) void prep_f16(const float* __restrict__ W1,
                                                const float* __restrict__ W2,
                                                _Float16* __restrict__ W1f,
                                                _Float16* __restrict__ W2f) {
    int idx = blockIdx.x * 256 + threadIdx.x;
    const int n1 = HDIM * DDIM;          // 32768
    if (idx < n1) {
        int h = idx >> 6, i = idx & 63;
        W1f[idx] = (_Float16)((i <= (h % 63)) ? W1[idx] : 0.0f);
    } else {
        int j = idx - n1;
        if (j < NCOLS * HDIM) {
            int o = j >> 9, hh = j & 511;
            W2f[j] = (_Float16)(((o / PDIM) > (hh % 63)) ? W2[j] : 0.0f);
        }
    }
}

// ---------------------------------------------------------------------------
// fast transcendentals (validated round 5)
// ---------------------------------------------------------------------------
__device__ __forceinline__ float fexp(float v)  { return __expf(v); }
__device__ __forceinline__ float flog(float v)  { return __logf(v); }
__device__ __forceinline__ float fdiv(float a, float b) { return __fdividef(a, b); }

// ---------------------------------------------------------------------------
// rational-quadratic spline (validated rounds 1-6)
// ---------------------------------------------------------------------------
__device__ __forceinline__ void rqs_eval(const float* prm, float xorig,
                                         float& yo, float& ldo) {
    const float xc = fminf(fmaxf(xorig, -RQ_BOUND), RQ_BOUND);
    const bool inside = (xorig >= -RQ_BOUND) && (xorig <= RQ_BOUND);

    float xk[KBINS + 1], yk[KBINS + 1], dd[KBINS + 1];
    {
        float m = prm[0];
        #pragma unroll
        for (int i = 1; i < KBINS; ++i) m = fmaxf(m, prm[i]);
        float e[KBINS]; float s = 0.0f;
        #pragma unroll
        for (int i = 0; i < KBINS; ++i) { e[i] = fexp(prm[i] - m); s += e[i]; }
        const float inv = fdiv(1.0f, s);
        float c = 0.0f;
        xk[0] = -RQ_BOUND;
        #pragma unroll
        for (int i = 0; i < KBINS; ++i) {
            float w = RQ_MINBIN + (1.0f - RQ_MINBIN * KBINS) * (e[i] * inv);
            c += w;
            xk[i + 1] = -RQ_BOUND + 2.0f * RQ_BOUND * c;
        }
        xk[KBINS] = RQ_BOUND;
    }
    {
        float m = prm[8];
        #pragma unroll
        for (int i = 1; i < KBINS; ++i) m = fmaxf(m, prm[8 + i]);
        float e[KBINS]; float s = 0.0f;
        #pragma unroll
        for (int i = 0; i < KBINS; ++i) { e[i] = fexp(prm[8 + i] - m); s += e[i]; }
        const float inv = fdiv(1.0f, s);
        float c = 0.0f;
        yk[0] = -RQ_BOUND;
        #pragma unroll
        for (int i = 0; i < KBINS; ++i) {
            float h = RQ_MINBIN + (1.0f - RQ_MINBIN * KBINS) * (e[i] * inv);
            c += h;
            yk[i + 1] = -RQ_BOUND + 2.0f * RQ_BOUND * c;
        }
        yk[KBINS] = RQ_BOUND;
    }
    dd[0] = 1.0f;
    #pragma unroll
    for (int i = 0; i < KBINS - 1; ++i) {
        const float v = prm[16 + i];
        const float e = fexp(-fabsf(v));
        dd[i + 1] = RQ_MINDER + flog(1.0f + e) + fmaxf(v, 0.0f);
    }
    dd[KBINS] = 1.0f;

    int idx = 0;
    #pragma unroll
    for (int i = 1; i < KBINS; ++i) idx += (xc >= xk[i]) ? 1 : 0;

    float x_k = xk[0], x_k1 = xk[1];
    float y_k = yk[0], y_k1 = yk[1];
    float d_k = dd[0], d_k1 = dd[1];
    #pragma unroll
    for (int i = 1; i < KBINS; ++i) {
        const bool mm = (idx == i);
        x_k  = mm ? xk[i]     : x_k;
        x_k1 = mm ? xk[i + 1] : x_k1;
        y_k  = mm ? yk[i]     : y_k;
        y_k1 = mm ? yk[i + 1] : y_k1;
        d_k  = mm ? dd[i]     : d_k;
        d_k1 = mm ? dd[i + 1] : d_k1;
    }

    const float w_k = x_k1 - x_k;
    const float h_k = y_k1 - y_k;
    const float rw  = fdiv(1.0f, w_k);
    const float s   = h_k * rw;
    const float th  = (xc - x_k) * rw;
    const float omt = 1.0f - th;
    const float t1m = th * omt;
    const float num = h_k * (s * th * th + d_k * t1m);
    const float den = s + (d_k1 + d_k - 2.0f * s) * t1m;
    const float yin = y_k + fdiv(num, den);
    const float dnum = s * s * (d_k1 * th * th + 2.0f * s * t1m + d_k * omt * omt);
    const float ldin = flog(dnum) - 2.0f * flog(den);

    yo  = inside ? yin : xorig;
    ldo = inside ? ldin : 0.0f;
}

// ---------------------------------------------------------------------------
// fused fp16 MFMA kernel: 32 rows/block, 512 threads (8 waves), 2 blocks/CU.
// Phase 2 barrier-free (wave-private 46-col strips, validated round 6).
// FIX vs round 6: z values buffered in 4 REGISTERS per lane during the chunk
// loop, flushed once at the end via an LDS transpose (reusing dead pstage)
// into full coalesced float4 rows — no partial-line scattered global writes
// (round 6's 345MB/175MB HBM RMW explosion).
// ---------------------------------------------------------------------------
__global__ __launch_bounds__(512, 4) void fused_flow(
    const float* __restrict__ x,  const float* __restrict__ b1,
    const float* __restrict__ b2, const _Float16* __restrict__ W1f,
    const _Float16* __restrict__ W2f,
    float* __restrict__ z_out, float* __restrict__ ld_out)
{
    __shared__ __align__(16) ushort_t hm[BM * 512];            // 32 KB, swizzled
    __shared__ __align__(16) float pstage[8 * BM * PSTRIDE];   // 47 KB (8 strips)
    // total 80896 B -> 2 blocks/CU; pstage reused at the end as
    //   zls[64][33] (transpose buffer) + ldbuf[32][8] at offset 2112

    const int t    = threadIdx.x;
    const int row0 = blockIdx.x * BM;
    const int wv   = t >> 6;
    const int lane = t & 63;
    const int l15  = lane & 15;
    const int lg   = lane >> 4;

    char*  hmB = (char*)hm;
    float* pw  = pstage + wv * (BM * PSTRIDE);   // this wave's private strip

    const int srow = lane & 31;   // spline row
    const int hi   = lane >> 5;   // spline d-within-strip (0/1)

    // hoisted spline x-reads (scattered 4B, L2-hot; latency hides under GEMM1)
    float xsp[4];
    #pragma unroll
    for (int c = 0; c < 4; ++c)
        xsp[c] = x[(size_t)(row0 + srow) * DDIM + (c * 16 + 2 * wv + hi)];

    // ---- phase 1: GEMM1 (x from global, W1f from global) -> hm fp16 ----
    {
        f32x4 acc1[4][2];
        #pragma unroll
        for (int j = 0; j < 4; ++j)
            #pragma unroll
            for (int m = 0; m < 2; ++m) acc1[j][m] = (f32x4){0.f, 0.f, 0.f, 0.f};

        #pragma unroll
        for (int kt = 0; kt < 2; ++kt) {
            half8 a[2];
            #pragma unroll
            for (int m = 0; m < 2; ++m) {
                const float* xr = x + (size_t)(row0 + m * 16 + l15) * DDIM + kt * 32 + lg * 8;
                const float4 xa = *(const float4*)(xr);
                const float4 xb = *(const float4*)(xr + 4);
                a[m][0] = (_Float16)xa.x; a[m][1] = (_Float16)xa.y;
                a[m][2] = (_Float16)xa.z; a[m][3] = (_Float16)xa.w;
                a[m][4] = (_Float16)xb.x; a[m][5] = (_Float16)xb.y;
                a[m][6] = (_Float16)xb.z; a[m][7] = (_Float16)xb.w;
            }
            #pragma unroll
            for (int j = 0; j < 4; ++j) {
                const int h = (wv * 4 + j) * 16 + l15;
                const half8 b = *(const half8*)(W1f + h * 64 + kt * 32 + lg * 8);
                #pragma unroll
                for (int m = 0; m < 2; ++m)
                    acc1[j][m] = __builtin_amdgcn_mfma_f32_16x16x32_f16(a[m], b, acc1[j][m], 0, 0, 0);
            }
        }
        #pragma unroll
        for (int j = 0; j < 4; ++j) {
            const int h = (wv * 4 + j) * 16 + l15;
            const float bias = b1[h];
            #pragma unroll
            for (int m = 0; m < 2; ++m) {
                #pragma unroll
                for (int q = 0; q < 4; ++q) {
                    const int r = m * 16 + lg * 4 + q;
                    const _Float16 hv = (_Float16)fmaxf(acc1[j][m][q] + bias, 0.0f);
                    *(ushort_t*)(hmB + r * 1024 + ((h * 2) ^ ((r & 7) << 4))) =
                        __builtin_bit_cast(ushort_t, hv);
                }
            }
        }
    }
    __syncthreads();   // hm is read-only from here on

    // ---- phase 2: per-wave GEMM2 strip + spline, 4 chunks, no barriers ----
    float ldacc = 0.0f;
    float zreg[4];

    int tb[3];
    #pragma unroll
    for (int i = 0; i < 3; ++i) {
        const int b = STRIPW * wv + 16 * i;
        tb[i] = (b > CHUNK - 16) ? (CHUNK - 16) : b;
    }

    #pragma unroll
    for (int c = 0; c < 4; ++c) {
        f32x4 acc[3][2];
        #pragma unroll
        for (int i = 0; i < 3; ++i)
            #pragma unroll
            for (int m = 0; m < 2; ++m) acc[i][m] = (f32x4){0.f, 0.f, 0.f, 0.f};

        const _Float16* w2p[3];
        #pragma unroll
        for (int i = 0; i < 3; ++i)
            w2p[i] = W2f + (size_t)(c * CHUNK + tb[i] + l15) * HDIM;

        #pragma unroll
        for (int kt = 0; kt < 16; ++kt) {
            half8 ah[2];
            #pragma unroll
            for (int m = 0; m < 2; ++m) {
                const int r  = m * 16 + l15;
                const int kb = (kt * 32 + lg * 8) * 2;
                ah[m] = *(const half8*)(hmB + r * 1024 + (kb ^ ((r & 7) << 4)));
            }
            half8 bfr[3];
            #pragma unroll
            for (int i = 0; i < 3; ++i)
                bfr[i] = *(const half8*)(w2p[i] + kt * 32 + lg * 8);
            #pragma unroll
            for (int i = 0; i < 3; ++i)
                #pragma unroll
                for (int m = 0; m < 2; ++m)
                    acc[i][m] = __builtin_amdgcn_mfma_f32_16x16x32_f16(ah[m], bfr[i], acc[i][m], 0, 0, 0);
        }

        // stage strip (wave-private; no barrier needed)
        #pragma unroll
        for (int i = 0; i < 3; ++i) {
            const int lcol = tb[i] + l15 - STRIPW * wv;   // dups write identical
            if (lcol < STRIPW) {
                #pragma unroll
                for (int m = 0; m < 2; ++m)
                    #pragma unroll
                    for (int q = 0; q < 4; ++q)
                        pw[(m * 16 + lg * 4 + q) * PSTRIDE + lcol] = acc[i][m][q];
            }
        }

        // spline: one (row, d) per lane; z stays in a register
        {
            const int d = c * 16 + 2 * wv + hi;
            float prm[PDIM];
            #pragma unroll
            for (int p = 0; p < PDIM; ++p)
                prm[p] = pw[srow * PSTRIDE + hi * PDIM + p] + b2[d * PDIM + p];
            float yv, lv;
            rqs_eval(prm, xsp[c], yv, lv);
            zreg[c] = yv;
            ldacc += lv;
        }
    }

    // ---- epilogue: coalesced z flush via LDS transpose + logdet reduce ----
    ldacc += __shfl_xor(ldacc, 32, 64);       // pair lanes sharing a row
    __syncthreads();                          // all waves done with pstage strips

    // zls[d][srow] with stride 33 (conflict-free scatter writes)
    #pragma unroll
    for (int c = 0; c < 4; ++c) {
        const int d = c * 16 + 2 * wv + hi;
        pstage[d * 33 + srow] = zreg[c];
    }
    if (lane < 32) pstage[2112 + srow * 8 + wv] = ldacc;   // ldbuf at offset 64*33
    __syncthreads();

    // z: thread t writes row t>>4, 4 consecutive d's — full float4 lines
    {
        const int r  = t >> 4;
        const int d0 = (t & 15) * 4;
        float4 zv;
        zv.x = pstage[(d0 + 0) * 33 + r];
        zv.y = pstage[(d0 + 1) * 33 + r];
        zv.z = pstage[(d0 + 2) * 33 + r];
        zv.w = pstage[(d0 + 3) * 33 + r];
        *(float4*)(z_out + (size_t)(row0 + r) * DDIM + d0) = zv;
    }
    if (t < BM) {
        float s = 0.0f;
        #pragma unroll
        for (int w = 0; w < 8; ++w) s += pstage[2112 + t * 8 + w];
        ld_out[row0 + t] = s;
    }
}

// ---------------------------------------------------------------------------
extern "C" void kernel_launch(void* const* d_in, const int* in_sizes, int n_in,
                              void* d_out, int out_size, void* d_ws, size_t ws_size,
                              hipStream_t stream) {
    (void)in_sizes; (void)n_in; (void)out_size; (void)ws_size;
    const float* x  = (const float*)d_in[0];
    const float* W1 = (const float*)d_in[1];
    const float* b1 = (const float*)d_in[2];
    const float* W2 = (const float*)d_in[3];
    const float* b2 = (const float*)d_in[4];

    _Float16* W1f = (_Float16*)d_ws;                 // 32768 fp16
    _Float16* W2f = W1f + HDIM * DDIM;               // 753664 fp16 (total ~1.57 MB)
    float* z  = (float*)d_out;
    float* ld = z + (size_t)NB * DDIM;

    const int n_prep = HDIM * DDIM + NCOLS * HDIM;   // 786432
    prep_f16<<<(n_prep + 255) / 256, 256, 0, stream>>>(W1, W2, W1f, W2f);
    fused_flow<<<NB / BM, 512, 0, stream>>>(x, b1, b2, W1f, W2f, z, ld);
}

// Round 8
// 203.196 us; speedup vs baseline: 1.4522x; 1.1762x over previous
//
#include <hip/hip_runtime.h>
#include <math.h>

#define NB    32768
#define DDIM  64
#define HDIM  512
#define PDIM  23        // 3*K - 1
#define KBINS 8
#define BM    32
#define NCOLS (DDIM * PDIM)   // 1472
#define CHUNK 368             // 23 n-tiles of 16 = 16 d's worth of params
#define PSTRIDE 372           // f32 per pstage row (368 + pad)

#define RQ_BOUND  4.0f
#define RQ_MINBIN 0.001f
#define RQ_MINDER 0.001f

typedef __attribute__((ext_vector_type(8))) _Float16 half8;
typedef __attribute__((ext_vector_type(4))) float f32x4;
typedef unsigned short ushort_t;

// ---------------------------------------------------------------------------
// prep: bake masks, convert to fp16.  M1[h,i] = i <= h%63 ; M2[o,h] = o/23 > h%63
// ---------------------------------------------------------------------------
__global__ __launch_bounds__(256) void prep_f16(const float* __restrict__ W1,
                                                const float* __restrict__ W2,
                                                _Float16* __restrict__ W1f,
                                                _Float16* __restrict__ W2f) {
    int idx = blockIdx.x * 256 + threadIdx.x;
    const int n1 = HDIM * DDIM;          // 32768
    if (idx < n1) {
        int h = idx >> 6, i = idx & 63;
        W1f[idx] = (_Float16)((i <= (h % 63)) ? W1[idx] : 0.0f);
    } else {
        int j = idx - n1;
        if (j < NCOLS * HDIM) {
            int o = j >> 9, hh = j & 511;
            W2f[j] = (_Float16)(((o / PDIM) > (hh % 63)) ? W2[j] : 0.0f);
        }
    }
}

// ---------------------------------------------------------------------------
// fast transcendentals (validated round 5)
// ---------------------------------------------------------------------------
__device__ __forceinline__ float fexp(float v)  { return __expf(v); }
__device__ __forceinline__ float flog(float v)  { return __logf(v); }
__device__ __forceinline__ float fdiv(float a, float b) { return __fdividef(a, b); }

// ---------------------------------------------------------------------------
// rational-quadratic spline (validated rounds 1-7)
// ---------------------------------------------------------------------------
__device__ __forceinline__ void rqs_eval(const float* prm, float xorig,
                                         float& yo, float& ldo) {
    const float xc = fminf(fmaxf(xorig, -RQ_BOUND), RQ_BOUND);
    const bool inside = (xorig >= -RQ_BOUND) && (xorig <= RQ_BOUND);

    float xk[KBINS + 1], yk[KBINS + 1], dd[KBINS + 1];
    {
        float m = prm[0];
        #pragma unroll
        for (int i = 1; i < KBINS; ++i) m = fmaxf(m, prm[i]);
        float e[KBINS]; float s = 0.0f;
        #pragma unroll
        for (int i = 0; i < KBINS; ++i) { e[i] = fexp(prm[i] - m); s += e[i]; }
        const float inv = fdiv(1.0f, s);
        float c = 0.0f;
        xk[0] = -RQ_BOUND;
        #pragma unroll
        for (int i = 0; i < KBINS; ++i) {
            float w = RQ_MINBIN + (1.0f - RQ_MINBIN * KBINS) * (e[i] * inv);
            c += w;
            xk[i + 1] = -RQ_BOUND + 2.0f * RQ_BOUND * c;
        }
        xk[KBINS] = RQ_BOUND;
    }
    {
        float m = prm[8];
        #pragma unroll
        for (int i = 1; i < KBINS; ++i) m = fmaxf(m, prm[8 + i]);
        float e[KBINS]; float s = 0.0f;
        #pragma unroll
        for (int i = 0; i < KBINS; ++i) { e[i] = fexp(prm[8 + i] - m); s += e[i]; }
        const float inv = fdiv(1.0f, s);
        float c = 0.0f;
        yk[0] = -RQ_BOUND;
        #pragma unroll
        for (int i = 0; i < KBINS; ++i) {
            float h = RQ_MINBIN + (1.0f - RQ_MINBIN * KBINS) * (e[i] * inv);
            c += h;
            yk[i + 1] = -RQ_BOUND + 2.0f * RQ_BOUND * c;
        }
        yk[KBINS] = RQ_BOUND;
    }
    dd[0] = 1.0f;
    #pragma unroll
    for (int i = 0; i < KBINS - 1; ++i) {
        const float v = prm[16 + i];
        const float e = fexp(-fabsf(v));
        dd[i + 1] = RQ_MINDER + flog(1.0f + e) + fmaxf(v, 0.0f);
    }
    dd[KBINS] = 1.0f;

    int idx = 0;
    #pragma unroll
    for (int i = 1; i < KBINS; ++i) idx += (xc >= xk[i]) ? 1 : 0;

    float x_k = xk[0], x_k1 = xk[1];
    float y_k = yk[0], y_k1 = yk[1];
    float d_k = dd[0], d_k1 = dd[1];
    #pragma unroll
    for (int i = 1; i < KBINS; ++i) {
        const bool mm = (idx == i);
        x_k  = mm ? xk[i]     : x_k;
        x_k1 = mm ? xk[i + 1] : x_k1;
        y_k  = mm ? yk[i]     : y_k;
        y_k1 = mm ? yk[i + 1] : y_k1;
        d_k  = mm ? dd[i]     : d_k;
        d_k1 = mm ? dd[i + 1] : d_k1;
    }

    const float w_k = x_k1 - x_k;
    const float h_k = y_k1 - y_k;
    const float rw  = fdiv(1.0f, w_k);
    const float s   = h_k * rw;
    const float th  = (xc - x_k) * rw;
    const float omt = 1.0f - th;
    const float t1m = th * omt;
    const float num = h_k * (s * th * th + d_k * t1m);
    const float den = s + (d_k1 + d_k - 2.0f * s) * t1m;
    const float yin = y_k + fdiv(num, den);
    const float dnum = s * s * (d_k1 * th * th + 2.0f * s * t1m + d_k * omt * omt);
    const float ldin = flog(dnum) - 2.0f * flog(den);

    yo  = inside ? yin : xorig;
    ldo = inside ? ldin : 0.0f;
}

// ---------------------------------------------------------------------------
// fused fp16 MFMA kernel — round-5 barriered structure (validated, clean
// memory traffic) + in-wave latency hiding:
//   * kt-loop software-pipelined with two register sets (issue loads for
//     kt+1 before MFMAs of kt)
//   * chunk c+1's kt=0 loads issued BEFORE the spline of chunk c (the ~600cy
//     spline VALU chain hides the cold-start L2 latency)
//   * s_setprio(1) around MFMA clusters (waves have role diversity now)
// ---------------------------------------------------------------------------
__global__ __launch_bounds__(512, 4) void fused_flow(
    const float* __restrict__ x,  const float* __restrict__ b1,
    const float* __restrict__ b2, const _Float16* __restrict__ W1f,
    const _Float16* __restrict__ W2f,
    float* __restrict__ z_out, float* __restrict__ ld_out)
{
    __shared__ __align__(16) ushort_t hm[BM * 512];      // 32 KB fp16, swizzled
    __shared__ __align__(16) float pstage[BM * PSTRIDE]; // 46.5 KB

    const int t    = threadIdx.x;
    const int row0 = blockIdx.x * BM;
    const int wv   = t >> 6;
    const int lane = t & 63;
    const int l15  = lane & 15;
    const int lg   = lane >> 4;

    char* hmB = (char*)hm;

    // ---- phase 1: GEMM1 (x from global, W1f from global) -> hm fp16 ----
    {
        f32x4 acc1[4][2];
        #pragma unroll
        for (int j = 0; j < 4; ++j)
            #pragma unroll
            for (int m = 0; m < 2; ++m) acc1[j][m] = (f32x4){0.f, 0.f, 0.f, 0.f};

        #pragma unroll
        for (int kt = 0; kt < 2; ++kt) {
            half8 a[2];
            #pragma unroll
            for (int m = 0; m < 2; ++m) {
                const float* xr = x + (size_t)(row0 + m * 16 + l15) * DDIM + kt * 32 + lg * 8;
                const float4 xa = *(const float4*)(xr);
                const float4 xb = *(const float4*)(xr + 4);
                a[m][0] = (_Float16)xa.x; a[m][1] = (_Float16)xa.y;
                a[m][2] = (_Float16)xa.z; a[m][3] = (_Float16)xa.w;
                a[m][4] = (_Float16)xb.x; a[m][5] = (_Float16)xb.y;
                a[m][6] = (_Float16)xb.z; a[m][7] = (_Float16)xb.w;
            }
            #pragma unroll
            for (int j = 0; j < 4; ++j) {
                const int h = (wv * 4 + j) * 16 + l15;
                const half8 b = *(const half8*)(W1f + h * 64 + kt * 32 + lg * 8);
                #pragma unroll
                for (int m = 0; m < 2; ++m)
                    acc1[j][m] = __builtin_amdgcn_mfma_f32_16x16x32_f16(a[m], b, acc1[j][m], 0, 0, 0);
            }
        }
        #pragma unroll
        for (int j = 0; j < 4; ++j) {
            const int h = (wv * 4 + j) * 16 + l15;
            const float bias = b1[h];
            #pragma unroll
            for (int m = 0; m < 2; ++m) {
                #pragma unroll
                for (int q = 0; q < 4; ++q) {
                    const int r = m * 16 + lg * 4 + q;
                    const _Float16 hv = (_Float16)fmaxf(acc1[j][m][q] + bias, 0.0f);
                    *(ushort_t*)(hmB + r * 1024 + ((h * 2) ^ ((r & 7) << 4))) =
                        __builtin_bit_cast(ushort_t, hv);
                }
            }
        }
    }
    __syncthreads();

    // ---- phase 2: GEMM2 + spline, 4 chunks, software-pipelined kt-loop ----
    float ldacc = 0.0f;
    const int srow = t >> 4;   // 0..31
    const int sd   = t & 15;   // 0..15
    const int tbase = wv * 3;

    // per-wave W2 base pointers (tile duplicated for wave 7's 3rd slot)
    const _Float16* w2base[3];
    #pragma unroll
    for (int i = 0; i < 3; ++i) {
        const int tile = (tbase + i < 23) ? (tbase + i) : 22;
        w2base[i] = W2f + (size_t)(tile * 16 + l15) * HDIM + lg * 8;
    }

    // load one kt-step's operands (2 LDS A-frags + 3 global B-frags)
    auto LOADSET = [&](int cc, int kt, half8 (&ah)[2], half8 (&bfr)[3]) {
        #pragma unroll
        for (int m = 0; m < 2; ++m) {
            const int r  = m * 16 + l15;
            const int kb = (kt * 32 + lg * 8) * 2;
            ah[m] = *(const half8*)(hmB + r * 1024 + (kb ^ ((r & 7) << 4)));
        }
        #pragma unroll
        for (int i = 0; i < 3; ++i)
            bfr[i] = *(const half8*)(w2base[i] + (size_t)cc * (CHUNK * HDIM) + kt * 32);
    };
    auto MFMASET = [&](half8 (&ah)[2], half8 (&bfr)[3], f32x4 (&acc)[3][2]) {
        __builtin_amdgcn_s_setprio(1);
        #pragma unroll
        for (int i = 0; i < 3; ++i)
            #pragma unroll
            for (int m = 0; m < 2; ++m)
                acc[i][m] = __builtin_amdgcn_mfma_f32_16x16x32_f16(ah[m], bfr[i], acc[i][m], 0, 0, 0);
        __builtin_amdgcn_s_setprio(0);
    };

    half8 ahA[2], bA[3], ahB[2], bB[3];
    LOADSET(0, 0, ahA, bA);   // prologue (after the GEMM1 barrier: hm ready)

    for (int c = 0; c < 4; ++c) {
        f32x4 acc[3][2];
        #pragma unroll
        for (int i = 0; i < 3; ++i)
            #pragma unroll
            for (int m = 0; m < 2; ++m) acc[i][m] = (f32x4){0.f, 0.f, 0.f, 0.f};

        // 16 kt steps in 8 pairs: loads for kt+1 issue before MFMAs of kt
        #pragma unroll
        for (int kp = 0; kp < 8; ++kp) {
            LOADSET(c, 2 * kp + 1, ahB, bB);
            MFMASET(ahA, bA, acc);
            if (kp < 7) LOADSET(c, 2 * kp + 2, ahA, bA);
            MFMASET(ahB, bB, acc);
        }

        __syncthreads();   // all waves done reading pstage (spline c-1)

        // stage full chunk (f32)
        #pragma unroll
        for (int i = 0; i < 3; ++i) {
            if (tbase + i < 23) {
                const int lcol = (tbase + i) * 16 + l15;
                #pragma unroll
                for (int m = 0; m < 2; ++m)
                    #pragma unroll
                    for (int q = 0; q < 4; ++q)
                        pstage[(m * 16 + lg * 4 + q) * PSTRIDE + lcol] = acc[i][m][q];
            }
        }
        __syncthreads();

        // prefetch next chunk's kt=0 operands BEFORE the spline: the ~600cy
        // spline chain hides the L2 latency (c=3: dead reload, harmless)
        LOADSET(c < 3 ? c + 1 : 3, 0, ahA, bA);

        // spline: one (row, d) per thread — 32 rows x 16 d's = 512
        {
            const int d = c * 16 + sd;
            float prm[PDIM];
            #pragma unroll
            for (int p = 0; p < PDIM; ++p)
                prm[p] = pstage[srow * PSTRIDE + sd * PDIM + p] + b2[d * PDIM + p];
            const float xv = x[(size_t)(row0 + srow) * DDIM + d];
            float yv, lv;
            rqs_eval(prm, xv, yv, lv);
            z_out[(size_t)(row0 + srow) * DDIM + d] = yv;
            ldacc += lv;
        }
        // no barrier here: next kt-loop doesn't touch pstage; stage(c+1) is
        // protected by the barrier after the next kt-loop.
    }

    // ---- logdet: sum the 16 threads of each row ----
    ldacc += __shfl_xor(ldacc, 1, 64);
    ldacc += __shfl_xor(ldacc, 2, 64);
    ldacc += __shfl_xor(ldacc, 4, 64);
    ldacc += __shfl_xor(ldacc, 8, 64);
    if (sd == 0) ld_out[row0 + srow] = ldacc;
}

// ---------------------------------------------------------------------------
extern "C" void kernel_launch(void* const* d_in, const int* in_sizes, int n_in,
                              void* d_out, int out_size, void* d_ws, size_t ws_size,
                              hipStream_t stream) {
    (void)in_sizes; (void)n_in; (void)out_size; (void)ws_size;
    const float* x  = (const float*)d_in[0];
    const float* W1 = (const float*)d_in[1];
    const float* b1 = (const float*)d_in[2];
    const float* W2 = (const float*)d_in[3];
    const float* b2 = (const float*)d_in[4];

    _Float16* W1f = (_Float16*)d_ws;                 // 32768 fp16
    _Float16* W2f = W1f + HDIM * DDIM;               // 753664 fp16 (total ~1.57 MB)
    float* z  = (float*)d_out;
    float* ld = z + (size_t)NB * DDIM;

    const int n_prep = HDIM * DDIM + NCOLS * HDIM;   // 786432
    prep_f16<<<(n_prep + 255) / 256, 256, 0, stream>>>(W1, W2, W1f, W2f);
    fused_flow<<<NB / BM, 512, 0, stream>>>(x, b1, b2, W1f, W2f, z, ld);
}